// Round 13
// baseline (48.353 us; speedup 1.0000x reference)
//
#include <hip/hip_runtime.h>
#include <hip/hip_bf16.h>

typedef __attribute__((ext_vector_type(8))) short bf16x8;
typedef __attribute__((ext_vector_type(4))) float f32x4;
typedef __attribute__((ext_vector_type(2))) float f32x2;
typedef unsigned int uint32;
typedef unsigned short ushort_t;
typedef __attribute__((ext_vector_type(4))) uint32 u32x4;
typedef __attribute__((ext_vector_type(2))) uint32 u32x2;

__device__ __forceinline__ ushort_t f2bf(float f) {
    unsigned int u = __float_as_uint(f);
    u = (u + 0x7FFFu + ((u >> 16) & 1u)) >> 16;
    return (ushort_t)u;
}

__device__ __forceinline__ uint32 cvt_pk_bf16(float lo, float hi) {
    uint32 r;
    asm("v_cvt_pk_bf16_f32 %0, %1, %2" : "=v"(r) : "v"(lo), "v"(hi));
    return r;
}

__device__ __forceinline__ void gload_lds16(const void* g, void* l) {
    __builtin_amdgcn_global_load_lds(
        (const __attribute__((address_space(1))) uint32*)g,
        (__attribute__((address_space(3))) uint32*)l, 16, 0, 0);
}

// Fused prep:
//  blocks 0..4095: transpose x NCHW fp32 -> NHWC bf16 with per-record 16B
//    sub-chunk XOR swizzle (chunk (c>>3) stored at (c>>3)^(x&7)) so LDS-window
//    ds_read_b128 gathers are bank-spread while staging stays linear.
//  blocks 4096..4671: repack weight fragment-major (R5 layout):
//    elem (tap, f, c=ks*32+lu*8+j) -> (((tap*4+ks)*4+lu)*128 + f)*8 + j
__global__ __launch_bounds__(256) void prep_all(const float* __restrict__ x,
                                                const float* __restrict__ w,
                                                ushort_t* __restrict__ xt,
                                                ushort_t* __restrict__ wT2) {
    int bi = blockIdx.x;
    int t = threadIdx.x;
    if (bi >= 4096) {
        int idx = (bi - 4096) * 256 + t;   // 0..147455
        int j  = idx & 7;
        int f  = (idx >> 3) & 127;
        int lu = (idx >> 10) & 3;
        int ks = (idx >> 12) & 3;
        int tap = idx >> 14;
        int c = ks * 32 + lu * 8 + j;
        wT2[idx] = f2bf(w[((size_t)f * 128 + c) * 9 + tap]);
        return;
    }
    __shared__ float tile[32][33];
    int b = bi & 7;
    int r2 = bi >> 3;
    int wb = r2 & 1, cb = (r2 >> 1) & 3, y = r2 >> 3;
    int lw = t & 31, lc = t >> 5;
    #pragma unroll
    for (int pass = 0; pass < 4; ++pass) {
        int c = cb * 32 + lc + pass * 8;
        tile[lc + pass * 8][lw] = x[(((size_t)b * 128 + c) * 64 + y) * 64 + wb * 32 + lw];
    }
    __syncthreads();
    int cc = t & 31, xl = t >> 5;
    #pragma unroll
    for (int pass = 0; pass < 4; ++pass) {
        int xll = xl + pass * 8;
        int xx = wb * 32 + xll;
        int c = cb * 32 + cc;
        int c2 = (((c >> 3) ^ (xx & 7)) << 3) | (c & 7);   // record-local swizzle
        xt[(((size_t)b * 64 + y) * 64 + xx) * 128 + c2] = f2bf(tile[cc][xll]);
    }
}

__device__ __forceinline__ bf16x8 interp4(u32x4 c0, u32x4 c1, u32x4 c2, u32x4 c3,
                                          f32x4 wv) {
    uint32 rr[4];
    #pragma unroll
    for (int i = 0; i < 4; ++i) {
        f32x2 a, s;
        uint32 u = c0[i];
        a.x = __uint_as_float(u << 16); a.y = __uint_as_float(u & 0xffff0000u);
        s = a * wv.x;
        u = c1[i];
        a.x = __uint_as_float(u << 16); a.y = __uint_as_float(u & 0xffff0000u);
        s += a * wv.y;
        u = c2[i];
        a.x = __uint_as_float(u << 16); a.y = __uint_as_float(u & 0xffff0000u);
        s += a * wv.z;
        u = c3[i];
        a.x = __uint_as_float(u << 16); a.y = __uint_as_float(u & 0xffff0000u);
        s += a * wv.w;
        rr[i] = cvt_pk_bf16(s.x, s.y);
    }
    u32x4 q = {rr[0], rr[1], rr[2], rr[3]};
    return __builtin_bit_cast(bf16x8, q);
}

// Block = 1024 thr = 16 waves = {4 ks} x {2 rowg} x {2 pxg}; one (b, row-pair).
// Wave = 128F x 32ch x 32px (2 B-tiles): gather/interp zero-dup, A-frag reused
// across 2 MFMAs, same-ks waves share A lines in L1.
// x gathers from an 8-row LDS window; encoded corner offsets precomputed.
// 256 blocks = exactly 1/CU, single round. LDS 155 KB.
__global__ __launch_bounds__(1024, 4) void dcn_main(
    const float* __restrict__ offset, const float* __restrict__ mask,
    const ushort_t* __restrict__ xt, const ushort_t* __restrict__ wT2,
    float* __restrict__ out)
{
    __shared__ __align__(16) char smem[158720];           // 155 KB
    ushort_t* xwin = (ushort_t*)smem;                     // [8][64][128] bf16 (128 KB)
    ushort_t* pwsl = (ushort_t*)(smem + 131072);          // [9][128][4] bf16 (9 KB)
    uint32*   posl = (uint32*)(smem + 140288);            // [9][128][4] u32 (18 KB)

    int bi = blockIdx.x;
    int b = bi & 7, rp = bi >> 3;            // batch <-> XCD; rp 0..31
    int ho0 = rp * 2;
    int row0 = min(max(ho0 - 3, 0), 56);     // window rows [row0, row0+8)
    int t = threadIdx.x, lane = t & 63, wid = t >> 6;
    int ks = wid >> 2, rowg = (wid >> 1) & 1, pxg = wid & 1;
    int p = lane & 15, lu = lane >> 4;
    int klu = (ks * 4 + lu) << 4;            // this lane's 16B slot offset

    const char* xgb = (const char*)xt + (size_t)b * (64 * 64 * 256);

    // ---- prologue: stage 8-row window (async) + encoded sampling params ----
    {
        const char* ws = xgb + ((size_t)row0 << 14);
        #pragma unroll
        for (int r = 0; r < 8; ++r)
            gload_lds16(ws + (r * 1024 + t) * 16, (char*)xwin + (r * 1024 + t) * 16);
    }
    for (int item = t; item < 1152; item += 1024) {
        int k = item >> 7, pxx = item & 127;
        int row = ho0 + (pxx >> 6), wo = pxx & 63;
        int ki = k / 3, kj = k - ki * 3;
        float dy = offset[(((size_t)b * 18 + 2 * k)     * 64 + row) * 64 + wo];
        float dx = offset[(((size_t)b * 18 + 2 * k + 1) * 64 + row) * 64 + wo];
        float m  = mask  [(((size_t)b * 9  + k)         * 64 + row) * 64 + wo];
        float py = (float)(row - 1 + ki) + dy;
        float px_ = (float)(wo - 1 + kj) + dx;
        float y0f = floorf(py), x0f = floorf(px_);
        float ly = py - y0f, lx = px_ - x0f;
        float hy = 1.f - ly, hx = 1.f - lx;
        int y0 = (int)y0f, x0 = (int)x0f;
        int y1 = y0 + 1, x1 = x0 + 1;
        float vy0 = (y0 >= 0 && y0 < 64) ? 1.f : 0.f;
        float vy1 = (y1 >= 0 && y1 < 64) ? 1.f : 0.f;
        float vx0 = (x0 >= 0 && x0 < 64) ? 1.f : 0.f;
        float vx1 = (x1 >= 0 && x1 < 64) ? 1.f : 0.f;
        int base = (k * 128 + pxx) * 4;
        pwsl[base + 0] = f2bf(hy * hx * m * vy0 * vx0);
        pwsl[base + 1] = f2bf(hy * lx * m * vy0 * vx1);
        pwsl[base + 2] = f2bf(ly * hx * m * vy1 * vx0);
        pwsl[base + 3] = f2bf(ly * lx * m * vy1 * vx1);
        int y0c = min(max(y0, 0), 63), y1c = min(max(y1, 0), 63);
        int x0c = min(max(x0, 0), 63), x1c = min(max(x1, 0), 63);
        #pragma unroll
        for (int c = 0; c < 4; ++c) {
            int yc = (c < 2) ? y0c : y1c;
            int xc = (c & 1) ? x1c : x0c;
            uint32 inw = ((unsigned)(yc - row0) < 8u) ? 0x80u : 0u;
            posl[base + c] = ((uint32)(yc * 64 + xc) << 8) | (uint32)(xc & 7) | inw;
        }
    }
    __syncthreads();   // window + params ready (drains global_load_lds)

    f32x4 acc[8][2];
    #pragma unroll
    for (int i = 0; i < 8; ++i) {
        acc[i][0] = (f32x4){0.f, 0.f, 0.f, 0.f};
        acc[i][1] = (f32x4){0.f, 0.f, 0.f, 0.f};
    }

    int rbase = row0 << 14;   // window byte origin in record space

    #pragma unroll 1
    for (int tap = 0; tap < 9; ++tap) {
        // ---- B frags for the wave's 2 pixel tiles ----
        bf16x8 bfr[2];
        #pragma unroll
        for (int tile = 0; tile < 2; ++tile) {
            int pxi = rowg * 64 + pxg * 32 + tile * 16 + p;
            int pb = (tap * 128 + pxi) * 4;
            u32x2 pw = *(const u32x2*)&pwsl[pb];
            f32x4 wv;
            wv.x = __uint_as_float(pw.x << 16);
            wv.y = __uint_as_float(pw.x & 0xffff0000u);
            wv.z = __uint_as_float(pw.y << 16);
            wv.w = __uint_as_float(pw.y & 0xffff0000u);
            u32x4 pv = *(const u32x4*)&posl[pb];
            u32x4 g[4];
            #pragma unroll
            for (int c = 0; c < 4; ++c) {
                uint32 v = pv[c];
                int off = klu ^ (((int)v & 7) << 4);
                int grec = (int)(v & 0xFFFFFF00u);
                bool inw = (v & 0x80u) != 0;
                const char* lp = (const char*)xwin + (inw ? (grec - rbase + off) : off);
                g[c] = *(const u32x4*)lp;
                if (!inw) {   // rare out-of-window fallback (exec-masked)
                    g[c] = *(const u32x4*)(xgb + grec + off);
                }
            }
            bfr[tile] = interp4(g[0], g[1], g[2], g[3], wv);
        }

        // ---- A frags from L2/L1-hot wT2; each feeds both B tiles ----
        const ushort_t* ab = wT2 + (size_t)(tap * 4 + ks) * 4096 + (lu * 128 + p) * 8;
        #pragma unroll
        for (int fq = 0; fq < 2; ++fq) {
            #pragma unroll
            for (int i = 0; i < 4; ++i) {
                int ft = fq * 4 + i;
                bf16x8 aa = *(const bf16x8*)(ab + ft * 128);
                acc[ft][0] = __builtin_amdgcn_mfma_f32_16x16x32_bf16(aa, bfr[0], acc[ft][0], 0, 0, 0);
                acc[ft][1] = __builtin_amdgcn_mfma_f32_16x16x32_bf16(aa, bfr[1], acc[ft][1], 0, 0, 0);
            }
        }
    }

    // ---- epilogue: 4-way ks reduce via LDS overlay, ks0 stores ----
    __syncthreads();
    float* red = (float*)smem;   // [2 slots][4 region][128 f][32 px] = 128 KB
    int region = rowg * 2 + pxg;

    #define DUMP(SLOT)                                                           \
        do {                                                                     \
            _Pragma("unroll")                                                    \
            for (int ft = 0; ft < 8; ++ft)                                       \
                _Pragma("unroll")                                                \
                for (int tile = 0; tile < 2; ++tile)                             \
                    _Pragma("unroll")                                            \
                    for (int r = 0; r < 4; ++r)                                  \
                        red[((((SLOT) * 4 + region) * 128 + ft * 16 + lu * 4 + r)\
                             * 32) + tile * 16 + p] = acc[ft][tile][r];          \
        } while (0)
    #define ADDIN(SLOT)                                                          \
        do {                                                                     \
            _Pragma("unroll")                                                    \
            for (int ft = 0; ft < 8; ++ft)                                       \
                _Pragma("unroll")                                                \
                for (int tile = 0; tile < 2; ++tile)                             \
                    _Pragma("unroll")                                            \
                    for (int r = 0; r < 4; ++r)                                  \
                        acc[ft][tile][r] += red[((((SLOT) * 4 + region) * 128    \
                            + ft * 16 + lu * 4 + r) * 32) + tile * 16 + p];      \
        } while (0)

    if (ks == 1) DUMP(0);
    if (ks == 3) DUMP(1);
    __syncthreads();
    if (ks == 0) ADDIN(0);
    if (ks == 2) ADDIN(1);
    __syncthreads();
    if (ks == 2) DUMP(0);
    __syncthreads();
    if (ks == 0) {
        ADDIN(0);
        float* outb = out + (size_t)b * 128 * 4096 + (ho0 + rowg) * 64 + pxg * 32;
        #pragma unroll
        for (int ft = 0; ft < 8; ++ft)
            #pragma unroll
            for (int tile = 0; tile < 2; ++tile)
                #pragma unroll
                for (int r = 0; r < 4; ++r) {
                    int f = ft * 16 + lu * 4 + r;
                    outb[(size_t)f * 4096 + tile * 16 + p] = acc[ft][tile][r];
                }
    }
    #undef DUMP
    #undef ADDIN
}

extern "C" void kernel_launch(void* const* d_in, const int* in_sizes, int n_in,
                              void* d_out, int out_size, void* d_ws, size_t ws_size,
                              hipStream_t stream) {
    const float* x      = (const float*)d_in[0];
    const float* offset = (const float*)d_in[1];
    const float* mask   = (const float*)d_in[2];
    const float* weight = (const float*)d_in[3];
    float* out = (float*)d_out;

    ushort_t* xt  = (ushort_t*)d_ws;                       // 8 MiB (swizzled NHWC)
    ushort_t* wT2 = xt + (size_t)8 * 64 * 64 * 128;        // 288 KiB
    if (ws_size < (size_t)(8 * 64 * 64 * 128 + 9 * 16384) * 2) return;

    prep_all<<<4672, 256, 0, stream>>>(x, weight, xt, wT2);
    dcn_main<<<256, 1024, 0, stream>>>(offset, mask, xt, wT2, out);
}

// Round 14
// 45.128 us; speedup vs baseline: 1.0715x; 1.0715x over previous
//
#include <hip/hip_runtime.h>
#include <hip/hip_bf16.h>

typedef __attribute__((ext_vector_type(8))) short bf16x8;
typedef __attribute__((ext_vector_type(4))) float f32x4;
typedef __attribute__((ext_vector_type(2))) float f32x2;
typedef unsigned int uint32;
typedef unsigned short ushort_t;
typedef __attribute__((ext_vector_type(4))) uint32 u32x4;

#define SB0() __builtin_amdgcn_sched_barrier(0)

__device__ __forceinline__ ushort_t f2bf(float f) {
    unsigned int u = __float_as_uint(f);
    u = (u + 0x7FFFu + ((u >> 16) & 1u)) >> 16;
    return (ushort_t)u;
}

__device__ __forceinline__ uint32 cvt_pk_bf16(float lo, float hi) {
    uint32 r;
    asm("v_cvt_pk_bf16_f32 %0, %1, %2" : "=v"(r) : "v"(lo), "v"(hi));
    return r;
}

__device__ __forceinline__ void gload_lds16(const void* g, void* l) {
    __builtin_amdgcn_global_load_lds(
        (const __attribute__((address_space(1))) uint32*)g,
        (__attribute__((address_space(3))) uint32*)l, 16, 0, 0);
}

// Fused prep:
//  blocks 0..4095: transpose x NCHW fp32 -> NHWC bf16 with per-record 16B
//    sub-chunk XOR swizzle (chunk (c>>3) stored at (c>>3)^(x&7)) so LDS-window
//    ds_read_b128 gathers are bank-spread while staging stays linear.
//  blocks 4096..4671: repack weight fragment-major (R5 layout):
//    elem (tap, f, c=ks*32+lu*8+j) -> (((tap*4+ks)*4+lu)*128 + f)*8 + j
__global__ __launch_bounds__(256) void prep_all(const float* __restrict__ x,
                                                const float* __restrict__ w,
                                                ushort_t* __restrict__ xt,
                                                ushort_t* __restrict__ wT2) {
    int bi = blockIdx.x;
    int t = threadIdx.x;
    if (bi >= 4096) {
        int idx = (bi - 4096) * 256 + t;   // 0..147455
        int j  = idx & 7;
        int f  = (idx >> 3) & 127;
        int lu = (idx >> 10) & 3;
        int ks = (idx >> 12) & 3;
        int tap = idx >> 14;
        int c = ks * 32 + lu * 8 + j;
        wT2[idx] = f2bf(w[((size_t)f * 128 + c) * 9 + tap]);
        return;
    }
    __shared__ float tile[32][33];
    int b = bi & 7;
    int r2 = bi >> 3;
    int wb = r2 & 1, cb = (r2 >> 1) & 3, y = r2 >> 3;
    int lw = t & 31, lc = t >> 5;
    #pragma unroll
    for (int pass = 0; pass < 4; ++pass) {
        int c = cb * 32 + lc + pass * 8;
        tile[lc + pass * 8][lw] = x[(((size_t)b * 128 + c) * 64 + y) * 64 + wb * 32 + lw];
    }
    __syncthreads();
    int cc = t & 31, xl = t >> 5;
    #pragma unroll
    for (int pass = 0; pass < 4; ++pass) {
        int xll = xl + pass * 8;
        int xx = wb * 32 + xll;
        int c = cb * 32 + cc;
        int c2 = (((c >> 3) ^ (xx & 7)) << 3) | (c & 7);   // record-local swizzle
        xt[(((size_t)b * 64 + y) * 64 + xx) * 128 + c2] = f2bf(tile[cc][xll]);
    }
}

__device__ __forceinline__ bf16x8 interp4(u32x4 c0, u32x4 c1, u32x4 c2, u32x4 c3,
                                          f32x4 wv) {
    uint32 rr[4];
    #pragma unroll
    for (int i = 0; i < 4; ++i) {
        f32x2 a, s;
        uint32 u = c0[i];
        a.x = __uint_as_float(u << 16); a.y = __uint_as_float(u & 0xffff0000u);
        s = a * wv.x;
        u = c1[i];
        a.x = __uint_as_float(u << 16); a.y = __uint_as_float(u & 0xffff0000u);
        s += a * wv.y;
        u = c2[i];
        a.x = __uint_as_float(u << 16); a.y = __uint_as_float(u & 0xffff0000u);
        s += a * wv.z;
        u = c3[i];
        a.x = __uint_as_float(u << 16); a.y = __uint_as_float(u & 0xffff0000u);
        s += a * wv.w;
        rr[i] = cvt_pk_bf16(s.x, s.y);
    }
    u32x4 q = {rr[0], rr[1], rr[2], rr[3]};
    return __builtin_bit_cast(bf16x8, q);
}

// Block = 1024 thr = 16 waves = {4 pxg} x {4 ks}; one (b,ho) row (64 px x 128 F).
// Wave tile: 16px x 128F x 32ch -- gather+interp zero-duplication.
// x gathers from a 7-row LDS window; A-frags from L2-hot wT2, PREFETCHED one
// tap ahead into ping-pong registers pinned with sched_barrier(0) so the
// global-load latency hides under the previous tap's gather+interp+MFMA.
// 124 KB LDS -> 1 block/CU = 16 waves = 4 waves/SIMD.
__global__ __launch_bounds__(1024, 4) void dcn_main(
    const float* __restrict__ offset, const float* __restrict__ mask,
    const ushort_t* __restrict__ xt, const ushort_t* __restrict__ wT2,
    float* __restrict__ out)
{
    __shared__ ushort_t xwin[7 * 64 * 128];  // 112 KB; overlaid by `red` in epilogue
    __shared__ float  pws_l[9][64][4];       // corner weights*mask*valid
    __shared__ uint32 pos_l[9][64];          // (y0*64+x0) | (y1*64+x1)<<16

    int bi = blockIdx.x;
    int b = bi & 7, ho = bi >> 3;            // batch <-> XCD
    int t = threadIdx.x, lane = t & 63, wid = t >> 6;
    int pxg = wid & 3, ks = wid >> 2;
    int p = lane & 15, lu = lane >> 4;
    int px = pxg * 16 + p;
    int row0 = min(max(ho - 3, 0), 57);

    const char* xgb = (const char*)xt + (size_t)b * (64 * 64 * 256);

    // ---- prologue: stage 7-row window (async) + sampling params ----
    {
        const char* ws = xgb + ((size_t)row0 << 14);     // row0*64*256
        #pragma unroll
        for (int r = 0; r < 7; ++r)
            gload_lds16(ws + (r * 1024 + t) * 16, (char*)xwin + (r * 1024 + t) * 16);
    }
    if (t < 576) {
        int k = t >> 6, pi = t & 63;
        int ki = k / 3, kj = k - ki * 3;
        float dy = offset[(((size_t)b * 18 + 2 * k)     * 64 + ho) * 64 + pi];
        float dx = offset[(((size_t)b * 18 + 2 * k + 1) * 64 + ho) * 64 + pi];
        float m  = mask  [(((size_t)b * 9  + k)         * 64 + ho) * 64 + pi];
        float py = (float)(ho - 1 + ki) + dy;
        float px_ = (float)(pi - 1 + kj) + dx;
        float y0f = floorf(py), x0f = floorf(px_);
        float ly = py - y0f, lx = px_ - x0f;
        float hy = 1.f - ly, hx = 1.f - lx;
        int y0 = (int)y0f, x0 = (int)x0f;
        int y1 = y0 + 1, x1 = x0 + 1;
        float vy0 = (y0 >= 0 && y0 < 64) ? 1.f : 0.f;
        float vy1 = (y1 >= 0 && y1 < 64) ? 1.f : 0.f;
        float vx0 = (x0 >= 0 && x0 < 64) ? 1.f : 0.f;
        float vx1 = (x1 >= 0 && x1 < 64) ? 1.f : 0.f;
        pws_l[k][pi][0] = hy * hx * m * vy0 * vx0;
        pws_l[k][pi][1] = hy * lx * m * vy0 * vx1;
        pws_l[k][pi][2] = ly * hx * m * vy1 * vx0;
        pws_l[k][pi][3] = ly * lx * m * vy1 * vx1;
        int y0c = min(max(y0, 0), 63), y1c = min(max(y1, 0), 63);
        int x0c = min(max(x0, 0), 63), x1c = min(max(x1, 0), 63);
        pos_l[k][pi] = (uint32)(y0c * 64 + x0c) | ((uint32)(y1c * 64 + x1c) << 16);
    }
    __syncthreads();   // window + params ready (drains global_load_lds)

    f32x4 acc[8];
    #pragma unroll
    for (int i = 0; i < 8; ++i) acc[i] = (f32x4){0.f, 0.f, 0.f, 0.f};

    int klu = ks * 64 + lu * 16;   // this lane's 16B slice within a 256B record
    const ushort_t* abase = wT2 + (lu * 128 + p) * 8;

    // A-frag prefetch: 8 plain 16B loads, pinned above SB0.
    #define LOADA(DST, T)                                                      \
        do {                                                                   \
            const ushort_t* ab_ = abase + (size_t)((T) * 4 + ks) * 4096;       \
            _Pragma("unroll")                                                  \
            for (int ft_ = 0; ft_ < 8; ++ft_)                                  \
                (DST)[ft_] = *(const bf16x8*)(ab_ + ft_ * 128);                \
        } while (0)

    // Gather + interp + 8 MFMA for tap T using A-regs AR.
    #define BODY(T, AR)                                                        \
        do {                                                                   \
            uint32 pp = pos_l[(T)][px];                                        \
            f32x4 wv = *(const f32x4*)pws_l[(T)][px];                          \
            int i00 = pp & 0xffffu, i11 = pp >> 16;                            \
            int y0c = i00 >> 6, x0c = i00 & 63;                                \
            int y1c = i11 >> 6, x1c = i11 & 63;                                \
            u32x4 g[4];                                                        \
            _Pragma("unroll")                                                  \
            for (int c = 0; c < 4; ++c) {                                      \
                int yc = (c < 2) ? y0c : y1c;                                  \
                int xc = (c & 1) ? x1c : x0c;                                  \
                int rl = yc - row0;                                            \
                int off = klu ^ ((xc & 7) << 4);                               \
                bool inw = (unsigned)rl < 7u;                                  \
                const char* lp = (const char*)xwin                             \
                    + (((inw ? rl : 0) * 64 + xc) << 8) + off;                 \
                g[c] = *(const u32x4*)lp;                                      \
                if (!inw) {                                                    \
                    const char* gp = xgb + (((size_t)yc * 64 + xc) << 8) + off;\
                    g[c] = *(const u32x4*)gp;                                  \
                }                                                              \
            }                                                                  \
            bf16x8 bb = interp4(g[0], g[1], g[2], g[3], wv);                   \
            _Pragma("unroll")                                                  \
            for (int ft_ = 0; ft_ < 8; ++ft_)                                  \
                acc[ft_] = __builtin_amdgcn_mfma_f32_16x16x32_bf16(            \
                    (AR)[ft_], bb, acc[ft_], 0, 0, 0);                         \
        } while (0)

    bf16x8 aP[8], aQ[8];
    LOADA(aP, 0);
    SB0();
    #pragma unroll 1
    for (int tp = 0; tp < 4; ++tp) {
        int t0 = tp * 2;
        LOADA(aQ, t0 + 1);   // prefetch next tap's A
        SB0();               // pin: loads stay above; latency hides under BODY
        BODY(t0, aP);
        LOADA(aP, t0 + 2);
        SB0();
        BODY(t0 + 1, aQ);
    }
    BODY(8, aP);
    #undef LOADA
    #undef BODY

    // ---- epilogue: 4-way ks reduce via LDS (overlay on xwin), ks0 stores ----
    __syncthreads();
    float* red = (float*)xwin;   // 2 slots x [128 f][64 px] = 64 KB <= 112 KB

    #define DUMP(SLOT)                                                          \
        do {                                                                    \
            _Pragma("unroll")                                                   \
            for (int ft = 0; ft < 8; ++ft)                                      \
                _Pragma("unroll")                                               \
                for (int r = 0; r < 4; ++r)                                     \
                    red[(SLOT) * 8192 + (ft * 16 + lu * 4 + r) * 64 + px] =     \
                        acc[ft][r];                                             \
        } while (0)
    #define ADDIN(SLOT)                                                         \
        do {                                                                    \
            _Pragma("unroll")                                                   \
            for (int ft = 0; ft < 8; ++ft)                                      \
                _Pragma("unroll")                                               \
                for (int r = 0; r < 4; ++r)                                     \
                    acc[ft][r] += red[(SLOT) * 8192                             \
                        + (ft * 16 + lu * 4 + r) * 64 + px];                    \
        } while (0)

    if (ks == 1) DUMP(0);
    if (ks == 3) DUMP(1);
    __syncthreads();
    if (ks == 0) ADDIN(0);
    if (ks == 2) ADDIN(1);
    __syncthreads();
    if (ks == 2) DUMP(0);
    __syncthreads();
    if (ks == 0) {
        ADDIN(0);
        float* outb = out + (size_t)b * 128 * 4096 + ho * 64;
        #pragma unroll
        for (int ft = 0; ft < 8; ++ft)
            #pragma unroll
            for (int r = 0; r < 4; ++r) {
                int f = ft * 16 + lu * 4 + r;
                outb[(size_t)f * 4096 + px] = acc[ft][r];
            }
    }
    #undef DUMP
    #undef ADDIN
}

extern "C" void kernel_launch(void* const* d_in, const int* in_sizes, int n_in,
                              void* d_out, int out_size, void* d_ws, size_t ws_size,
                              hipStream_t stream) {
    const float* x      = (const float*)d_in[0];
    const float* offset = (const float*)d_in[1];
    const float* mask   = (const float*)d_in[2];
    const float* weight = (const float*)d_in[3];
    float* out = (float*)d_out;

    ushort_t* xt  = (ushort_t*)d_ws;                       // 8 MiB (swizzled NHWC)
    ushort_t* wT2 = xt + (size_t)8 * 64 * 64 * 128;        // 288 KiB
    if (ws_size < (size_t)(8 * 64 * 64 * 128 + 9 * 16384) * 2) return;

    prep_all<<<4672, 256, 0, stream>>>(x, weight, xt, wT2);
    dcn_main<<<512, 1024, 0, stream>>>(offset, mask, xt, wT2, out);
}

// Round 15
// 41.132 us; speedup vs baseline: 1.1756x; 1.0971x over previous
//
#include <hip/hip_runtime.h>
#include <hip/hip_bf16.h>

typedef __attribute__((ext_vector_type(8))) short bf16x8;
typedef __attribute__((ext_vector_type(4))) float f32x4;
typedef __attribute__((ext_vector_type(2))) float f32x2;
typedef unsigned int uint32;
typedef unsigned short ushort_t;
typedef __attribute__((ext_vector_type(4))) uint32 u32x4;

__device__ __forceinline__ ushort_t f2bf(float f) {
    unsigned int u = __float_as_uint(f);
    u = (u + 0x7FFFu + ((u >> 16) & 1u)) >> 16;
    return (ushort_t)u;
}

__device__ __forceinline__ uint32 cvt_pk_bf16(float lo, float hi) {
    uint32 r;
    asm("v_cvt_pk_bf16_f32 %0, %1, %2" : "=v"(r) : "v"(lo), "v"(hi));
    return r;
}

__device__ __forceinline__ void gload_lds16(const void* g, void* l) {
    __builtin_amdgcn_global_load_lds(
        (const __attribute__((address_space(1))) uint32*)g,
        (__attribute__((address_space(3))) uint32*)l, 16, 0, 0);
}

// Fused prep (unchanged from R12):
//  blocks 0..4095: transpose x NCHW fp32 -> NHWC bf16 with per-record 16B
//    sub-chunk XOR swizzle (chunk (c>>3) stored at (c>>3)^(x&7)).
//  blocks 4096..4671: repack weight fragment-major (R5 layout).
__global__ __launch_bounds__(256) void prep_all(const float* __restrict__ x,
                                                const float* __restrict__ w,
                                                ushort_t* __restrict__ xt,
                                                ushort_t* __restrict__ wT2) {
    int bi = blockIdx.x;
    int t = threadIdx.x;
    if (bi >= 4096) {
        int idx = (bi - 4096) * 256 + t;   // 0..147455
        int j  = idx & 7;
        int f  = (idx >> 3) & 127;
        int lu = (idx >> 10) & 3;
        int ks = (idx >> 12) & 3;
        int tap = idx >> 14;
        int c = ks * 32 + lu * 8 + j;
        wT2[idx] = f2bf(w[((size_t)f * 128 + c) * 9 + tap]);
        return;
    }
    __shared__ float tile[32][33];
    int b = bi & 7;
    int r2 = bi >> 3;
    int wb = r2 & 1, cb = (r2 >> 1) & 3, y = r2 >> 3;
    int lw = t & 31, lc = t >> 5;
    #pragma unroll
    for (int pass = 0; pass < 4; ++pass) {
        int c = cb * 32 + lc + pass * 8;
        tile[lc + pass * 8][lw] = x[(((size_t)b * 128 + c) * 64 + y) * 64 + wb * 32 + lw];
    }
    __syncthreads();
    int cc = t & 31, xl = t >> 5;
    #pragma unroll
    for (int pass = 0; pass < 4; ++pass) {
        int xll = xl + pass * 8;
        int xx = wb * 32 + xll;
        int c = cb * 32 + cc;
        int c2 = (((c >> 3) ^ (xx & 7)) << 3) | (c & 7);   // record-local swizzle
        xt[(((size_t)b * 64 + y) * 64 + xx) * 128 + c2] = f2bf(tile[cc][xll]);
    }
}

__device__ __forceinline__ bf16x8 interp4(u32x4 c0, u32x4 c1, u32x4 c2, u32x4 c3,
                                          f32x4 wv) {
    uint32 rr[4];
    #pragma unroll
    for (int i = 0; i < 4; ++i) {
        f32x2 a, s;
        uint32 u = c0[i];
        a.x = __uint_as_float(u << 16); a.y = __uint_as_float(u & 0xffff0000u);
        s = a * wv.x;
        u = c1[i];
        a.x = __uint_as_float(u << 16); a.y = __uint_as_float(u & 0xffff0000u);
        s += a * wv.y;
        u = c2[i];
        a.x = __uint_as_float(u << 16); a.y = __uint_as_float(u & 0xffff0000u);
        s += a * wv.z;
        u = c3[i];
        a.x = __uint_as_float(u << 16); a.y = __uint_as_float(u & 0xffff0000u);
        s += a * wv.w;
        rr[i] = cvt_pk_bf16(s.x, s.y);
    }
    u32x4 q = {rr[0], rr[1], rr[2], rr[3]};
    return __builtin_bit_cast(bf16x8, q);
}

// Block = 1024 thr = 16 waves = {4 pxg} x {4 ks}; one (b,ho) row (64 px x 128 F).
// Wave tile: 16px x 128F x 32ch, zero gather/interp duplication.
// 9-row LDS window (wave-level fallback prob ~4%, execz-skipped); 2-tap
// interleaved pipeline (2 independent gather chains per iteration); epilogue
// reduce stride 65 (bank-conflict-free). 159 KB LDS -> 1 block/CU.
__global__ __launch_bounds__(1024, 4) void dcn_main(
    const float* __restrict__ offset, const float* __restrict__ mask,
    const ushort_t* __restrict__ xt, const ushort_t* __restrict__ wT2,
    float* __restrict__ out)
{
    __shared__ ushort_t xwin[9 * 64 * 128];  // 144 KB; overlaid by `red` in epilogue
    __shared__ float  pws_l[9][64][4];       // 9 KB
    __shared__ uint32 pos_l[9][64];          // 2.25 KB

    int bi = blockIdx.x;
    int b = bi & 7, ho = bi >> 3;            // batch <-> XCD
    int t = threadIdx.x, lane = t & 63, wid = t >> 6;
    int pxg = wid & 3, ks = wid >> 2;
    int p = lane & 15, lu = lane >> 4;
    int px = pxg * 16 + p;
    int row0 = min(max(ho - 4, 0), 55);      // window rows [row0, row0+9)

    const char* xgb = (const char*)xt + (size_t)b * (64 * 64 * 256);

    // ---- prologue: stage 9-row window (async) + sampling params ----
    {
        const char* ws = xgb + ((size_t)row0 << 14);
        #pragma unroll
        for (int r = 0; r < 9; ++r)
            gload_lds16(ws + (r * 1024 + t) * 16, (char*)xwin + (r * 1024 + t) * 16);
    }
    if (t < 576) {
        int k = t >> 6, pi = t & 63;
        int ki = k / 3, kj = k - ki * 3;
        float dy = offset[(((size_t)b * 18 + 2 * k)     * 64 + ho) * 64 + pi];
        float dx = offset[(((size_t)b * 18 + 2 * k + 1) * 64 + ho) * 64 + pi];
        float m  = mask  [(((size_t)b * 9  + k)         * 64 + ho) * 64 + pi];
        float py = (float)(ho - 1 + ki) + dy;
        float px_ = (float)(pi - 1 + kj) + dx;
        float y0f = floorf(py), x0f = floorf(px_);
        float ly = py - y0f, lx = px_ - x0f;
        float hy = 1.f - ly, hx = 1.f - lx;
        int y0 = (int)y0f, x0 = (int)x0f;
        int y1 = y0 + 1, x1 = x0 + 1;
        float vy0 = (y0 >= 0 && y0 < 64) ? 1.f : 0.f;
        float vy1 = (y1 >= 0 && y1 < 64) ? 1.f : 0.f;
        float vx0 = (x0 >= 0 && x0 < 64) ? 1.f : 0.f;
        float vx1 = (x1 >= 0 && x1 < 64) ? 1.f : 0.f;
        pws_l[k][pi][0] = hy * hx * m * vy0 * vx0;
        pws_l[k][pi][1] = hy * lx * m * vy0 * vx1;
        pws_l[k][pi][2] = ly * hx * m * vy1 * vx0;
        pws_l[k][pi][3] = ly * lx * m * vy1 * vx1;
        int y0c = min(max(y0, 0), 63), y1c = min(max(y1, 0), 63);
        int x0c = min(max(x0, 0), 63), x1c = min(max(x1, 0), 63);
        pos_l[k][pi] = (uint32)(y0c * 64 + x0c) | ((uint32)(y1c * 64 + x1c) << 16);
    }
    __syncthreads();   // window + params ready (drains global_load_lds)

    f32x4 acc[8];
    #pragma unroll
    for (int i = 0; i < 8; ++i) acc[i] = (f32x4){0.f, 0.f, 0.f, 0.f};

    int klu = ks * 64 + lu * 16;   // this lane's 16B slice within a 256B record
    const ushort_t* abase = wT2 + (lu * 128 + p) * 8;

    // Phase A: compute corner records + issue the 4 window ds_reads for tap T.
    #define GATHER_LDS(T, G, REC)                                              \
        do {                                                                   \
            uint32 pp = pos_l[(T)][px];                                        \
            int i00 = pp & 0xffffu, i11 = pp >> 16;                            \
            int y0c = i00 >> 6, x0c = i00 & 63;                                \
            int y1c = i11 >> 6, x1c = i11 & 63;                                \
            _Pragma("unroll")                                                  \
            for (int c = 0; c < 4; ++c) {                                      \
                int yc = (c < 2) ? y0c : y1c;                                  \
                int xc = (c & 1) ? x1c : x0c;                                  \
                int rl = yc - row0;                                            \
                int off = klu ^ ((xc & 7) << 4);                               \
                (REC)[c] = (uint32)(((yc * 64 + xc) << 8) + off)               \
                           | (((unsigned)rl < 9u) ? 0x80000000u : 0u);         \
                const char* lp = (const char*)xwin                             \
                    + ((((unsigned)rl < 9u ? rl : 0) * 64 + xc) << 8) + off;   \
                (G)[c] = *(const u32x4*)lp;                                    \
            }                                                                  \
        } while (0)

    // Phase B: rare out-of-window fixup (execz-skipped ~96% of the time).
    #define GATHER_FIX(G, REC)                                                 \
        do {                                                                   \
            _Pragma("unroll")                                                  \
            for (int c = 0; c < 4; ++c) {                                      \
                if (!((REC)[c] & 0x80000000u)) {                               \
                    (G)[c] = *(const u32x4*)(xgb + ((REC)[c] & 0x7fffffffu));  \
                }                                                              \
            }                                                                  \
        } while (0)

    #define MFMA8(T, BB)                                                       \
        do {                                                                   \
            const ushort_t* ab_ = abase + (size_t)((T) * 4 + ks) * 4096;       \
            _Pragma("unroll")                                                  \
            for (int ft_ = 0; ft_ < 8; ++ft_) {                                \
                bf16x8 aa = *(const bf16x8*)(ab_ + ft_ * 128);                 \
                acc[ft_] = __builtin_amdgcn_mfma_f32_16x16x32_bf16(            \
                    aa, (BB), acc[ft_], 0, 0, 0);                              \
            }                                                                  \
        } while (0)

    #pragma unroll 1
    for (int pr = 0; pr < 4; ++pr) {
        int t0 = pr * 2;
        u32x4 g0[4], g1[4];
        uint32 rec0[4], rec1[4];
        GATHER_LDS(t0, g0, rec0);        // chain 0: 4 ds_read_b128
        GATHER_LDS(t0 + 1, g1, rec1);    // chain 1: 4 ds_read_b128 (independent)
        GATHER_FIX(g0, rec0);
        GATHER_FIX(g1, rec1);
        f32x4 wv0 = *(const f32x4*)pws_l[t0][px];
        f32x4 wv1 = *(const f32x4*)pws_l[t0 + 1][px];
        bf16x8 b0 = interp4(g0[0], g0[1], g0[2], g0[3], wv0);
        bf16x8 b1 = interp4(g1[0], g1[1], g1[2], g1[3], wv1);
        MFMA8(t0, b0);
        MFMA8(t0 + 1, b1);
    }
    {   // tap 8
        u32x4 g0[4];
        uint32 rec0[4];
        GATHER_LDS(8, g0, rec0);
        GATHER_FIX(g0, rec0);
        f32x4 wv0 = *(const f32x4*)pws_l[8][px];
        bf16x8 b0 = interp4(g0[0], g0[1], g0[2], g0[3], wv0);
        MFMA8(8, b0);
    }
    #undef GATHER_LDS
    #undef GATHER_FIX
    #undef MFMA8

    // ---- epilogue: 4-way ks reduce via LDS (overlay on xwin), stride 65 ----
    __syncthreads();
    float* red = (float*)xwin;   // 2 slots x [128 f][stride 65] = 66.5 KB <= 144 KB

    #define DUMP(SLOT)                                                          \
        do {                                                                    \
            _Pragma("unroll")                                                   \
            for (int ft = 0; ft < 8; ++ft)                                      \
                _Pragma("unroll")                                               \
                for (int r = 0; r < 4; ++r)                                     \
                    red[(SLOT) * 8320 + (ft * 16 + lu * 4 + r) * 65 + px] =     \
                        acc[ft][r];                                             \
        } while (0)
    #define ADDIN(SLOT)                                                         \
        do {                                                                    \
            _Pragma("unroll")                                                   \
            for (int ft = 0; ft < 8; ++ft)                                      \
                _Pragma("unroll")                                               \
                for (int r = 0; r < 4; ++r)                                     \
                    acc[ft][r] += red[(SLOT) * 8320                             \
                        + (ft * 16 + lu * 4 + r) * 65 + px];                    \
        } while (0)

    if (ks == 1) DUMP(0);
    if (ks == 3) DUMP(1);
    __syncthreads();
    if (ks == 0) ADDIN(0);
    if (ks == 2) ADDIN(1);
    __syncthreads();
    if (ks == 2) DUMP(0);
    __syncthreads();
    if (ks == 0) {
        ADDIN(0);
        float* outb = out + (size_t)b * 128 * 4096 + ho * 64;
        #pragma unroll
        for (int ft = 0; ft < 8; ++ft)
            #pragma unroll
            for (int r = 0; r < 4; ++r) {
                int f = ft * 16 + lu * 4 + r;
                outb[(size_t)f * 4096 + px] = acc[ft][r];
            }
    }
    #undef DUMP
    #undef ADDIN
}

extern "C" void kernel_launch(void* const* d_in, const int* in_sizes, int n_in,
                              void* d_out, int out_size, void* d_ws, size_t ws_size,
                              hipStream_t stream) {
    const float* x      = (const float*)d_in[0];
    const float* offset = (const float*)d_in[1];
    const float* mask   = (const float*)d_in[2];
    const float* weight = (const float*)d_in[3];
    float* out = (float*)d_out;

    ushort_t* xt  = (ushort_t*)d_ws;                       // 8 MiB (swizzled NHWC)
    ushort_t* wT2 = xt + (size_t)8 * 64 * 64 * 128;        // 288 KiB
    if (ws_size < (size_t)(8 * 64 * 64 * 128 + 9 * 16384) * 2) return;

    prep_all<<<4672, 256, 0, stream>>>(x, weight, xt, wT2);
    dcn_main<<<512, 1024, 0, stream>>>(offset, mask, xt, wT2, out);
}